// Round 6
// baseline (1687.437 us; speedup 1.0000x reference)
//
#include <hip/hip_runtime.h>
#include <math.h>

// ---------------------------------------------------------------------------
// FRU cell, decomposed:
//   state[f,s](t) = sum_{tau<=t} c_f(tau)*stats[s](tau)   (f>=1; f=0: current only)
//   c_f(t) = (1/L)*cos((2pi/L)*t*f + 2pi*phases[f])
// Scan only carries: Pa[r] = state_acc@Wr  (64 floats) and stats(t-1) (64 floats).
//   recur(t)  = gelu(Pa(t-1) + c0*stats(t-1)@Wr0 + br)
//   stats(t)  = gelu(xstat[b,t] + recur@Wsr + bs)
//   Pa(t)     = Pa(t-1) + stats(t)@M_t,  M_t precomputed (bf16, streamed)
// k_scan v6 = v5 (4-wave split per batch, DPP quad reduce, rcp-gelu, pk-FMA,
// RAW lgkm-only barriers, 2-deep register ring prefetch) + TWO batches per
// 512-thread workgroup: 8 waves = 2 per SIMD, so co-resident waves hide each
// other's LDS/DPP/trans latency (v5 had 1 wave/SIMD = zero latency hiding;
// 37% issue rate, ~580cy/step exposed stall).
// Then: state materialized bf16 (cumsum over t), out = gelu(state@Wo + bo) as
// one big bf16 MFMA GEMM.
// ---------------------------------------------------------------------------

#define TWO_PI 6.283185307179586f
#define INV_L  (1.0f/2048.0f)

typedef unsigned short u16;
typedef __attribute__((ext_vector_type(8))) short bf16x8;   // 8 bf16 = 4 VGPRs
typedef __attribute__((ext_vector_type(4))) float f32x4;
typedef __attribute__((ext_vector_type(2))) float f32x2;

__device__ __forceinline__ float bf2f(u16 u){ return __uint_as_float(((unsigned int)u) << 16); }
__device__ __forceinline__ u16 f2bf(float x){
  unsigned int u = __float_as_uint(x);
  u += 0x7FFFu + ((u >> 16) & 1u);           // round-to-nearest-even
  return (u16)(u >> 16);
}
// unpack a dword holding 2 bf16 into a float2 (lo, hi)
__device__ __forceinline__ f32x2 bf2x2(unsigned int d){
  f32x2 v;
  v.x = __uint_as_float(d << 16);
  v.y = __uint_as_float(d & 0xffff0000u);
  return v;
}
__device__ __forceinline__ f32x2 fma2(f32x2 a, f32x2 b, f32x2 c){
#if defined(__has_builtin)
#if __has_builtin(__builtin_elementwise_fma)
  return __builtin_elementwise_fma(a, b, c);
#else
  return (f32x2){fmaf(a.x, b.x, c.x), fmaf(a.y, b.y, c.y)};
#endif
#else
  return (f32x2){fmaf(a.x, b.x, c.x), fmaf(a.y, b.y, c.y)};
#endif
}
// butterfly sum over the 4-lane quad via DPP quad_perm (VALU pipe, no DS ops)
__device__ __forceinline__ float qred(float x){
  x += __uint_as_float(__builtin_amdgcn_mov_dpp(__float_as_uint(x), 0xB1, 0xF, 0xF, true)); // xor1
  x += __uint_as_float(__builtin_amdgcn_mov_dpp(__float_as_uint(x), 0x4E, 0xF, 0xF, true)); // xor2
  return x;
}
// tanh-approx gelu, algebraically = 0.5x(1+tanh(y)) = x*e/(e+1), e=exp(2y).
// err <3e-4 abs (same approx as before; rcp adds ~1e-7). Attenuated ~50x
// through the (1/L) cumsum.
__device__ __forceinline__ float gelu_fast(float x){
  float x2 = x * x;
  float z = x * fmaf(0.07135481627f, x2, 1.5957691216f);   // z = 2y
  z = fminf(fmaxf(z, -24.0f), 24.0f);
  float e = __expf(z);
  return x * e * __builtin_amdgcn_rcpf(e + 1.0f);
}
__device__ __forceinline__ float gelu_erf(float x){
  return 0.5f * x * (1.0f + erff(x * 0.7071067811865475f));
}

// --------------------------- K2: M_t + ctab precompute ----------------------
// MT[slot=t-1][r][s] (bf16) = sum_{f=1..15} c_f(t) * Wr[(f*64+s)*64 + r]
// ctab[t][f] = c_f(t), t in [1,2048]
__global__ __launch_bounds__(256) void k_mprep(const float* __restrict__ Wr,
    const float* __restrict__ phases, u16* __restrict__ MT, float* __restrict__ ctab){
  int slot = blockIdx.x;                 // tau = slot+1
  float tau = (float)(slot + 1);
  __shared__ float cf[16];
  int tid = threadIdx.x;
  if (tid < 16){
    float c = INV_L * cosf((TWO_PI * INV_L) * tau * (float)tid + TWO_PI * phases[tid]);
    cf[tid] = c;
    ctab[(slot + 1) * 16 + tid] = c;
  }
  __syncthreads();
  int r = tid & 63, s0 = (tid >> 6) * 16;
  float acc[16];
#pragma unroll
  for (int i = 0; i < 16; ++i) acc[i] = 0.0f;
  for (int f = 1; f < 16; ++f){
    float c = cf[f];
    const float* wp = Wr + (f * 64 + s0) * 64 + r;   // coalesced over r (lanes)
#pragma unroll
    for (int i = 0; i < 16; ++i) acc[i] += c * wp[i * 64];
  }
  u16* o = MT + ((size_t)slot * 64 + r) * 64 + s0;
  uint4 p0, p1;
  p0.x = (unsigned)f2bf(acc[0])  | ((unsigned)f2bf(acc[1])  << 16);
  p0.y = (unsigned)f2bf(acc[2])  | ((unsigned)f2bf(acc[3])  << 16);
  p0.z = (unsigned)f2bf(acc[4])  | ((unsigned)f2bf(acc[5])  << 16);
  p0.w = (unsigned)f2bf(acc[6])  | ((unsigned)f2bf(acc[7])  << 16);
  p1.x = (unsigned)f2bf(acc[8])  | ((unsigned)f2bf(acc[9])  << 16);
  p1.y = (unsigned)f2bf(acc[10]) | ((unsigned)f2bf(acc[11]) << 16);
  p1.z = (unsigned)f2bf(acc[12]) | ((unsigned)f2bf(acc[13]) << 16);
  p1.w = (unsigned)f2bf(acc[14]) | ((unsigned)f2bf(acc[15]) << 16);
  ((uint4*)o)[0] = p0;
  ((uint4*)o)[1] = p1;
}

// --------------------------- K1: xstat = x @ Ws[0:128,:] --------------------
__global__ __launch_bounds__(256) void k_xstat(const float* __restrict__ x,
    const float* __restrict__ Ws, float* __restrict__ xstat){
  __shared__ float4 xt4[64 * 32];        // 64 rows x 128 cols
  __shared__ float partial[4][64];
  int tid = threadIdx.x;
  int row0 = blockIdx.x * 64;
  const float4* xg = (const float4*)(x + (size_t)row0 * 128);
  for (int i = tid; i < 2048; i += 256) xt4[i] = xg[i];
  int s = tid & 63, kq = tid >> 6;       // K split 4 x 32
  float wk[32];
#pragma unroll
  for (int j = 0; j < 32; ++j) wk[j] = Ws[(kq * 32 + j) * 64 + s];
  __syncthreads();
  for (int rr = 0; rr < 64; ++rr){
    const float4* xr = &xt4[rr * 32 + kq * 8];
    float a = 0.0f;
#pragma unroll
    for (int j = 0; j < 8; ++j){
      float4 v = xr[j];
      a += v.x * wk[j*4] + v.y * wk[j*4+1] + v.z * wk[j*4+2] + v.w * wk[j*4+3];
    }
    partial[kq][s] = a;
    __syncthreads();
    if (tid < 64)
      xstat[(size_t)(row0 + rr) * 64 + tid] =
        partial[0][tid] + partial[1][tid] + partial[2][tid] + partial[3][tid];
    __syncthreads();
  }
}

// --------------------------- K4b: WoT[n][k] = bf16(Wo[k][n]) ----------------
__global__ __launch_bounds__(256) void k_wot(const float* __restrict__ Wo, u16* __restrict__ WoT){
  __shared__ float tile[64][65];
  int bx = blockIdx.x & 15, by = blockIdx.x >> 4;
  int k0 = bx * 64, n0 = by * 64;
  int tid = threadIdx.x, ln = tid & 63, w = tid >> 6;
#pragma unroll
  for (int i = 0; i < 16; ++i){
    int kk = w * 16 + i;
    tile[kk][ln] = Wo[(size_t)(k0 + kk) * 1024 + n0 + ln];
  }
  __syncthreads();
#pragma unroll
  for (int i = 0; i < 16; ++i){
    int nn = w * 16 + i;
    WoT[(size_t)(n0 + nn) * 1024 + k0 + ln] = f2bf(tile[ln][nn]);
  }
}

// --------------------------- K3: the sequential scan ------------------------
// TWO batches per 512-thread workgroup (sub-group g = tid>>8 of 4 waves each,
// 8 waves total = 2 per SIMD for latency hiding). Within a sub-group:
// idx = w*16 + (l>>2) is the output index (r in stage A, s in stage B);
// q = l&3 splits K=64 into 4x16, reduced with DPP quad_perm butterflies.
// RAW barrier: waits DS only; global prefetch stays outstanding across it.
#define BARRIER_LG() asm volatile("s_waitcnt lgkmcnt(0)\n\ts_barrier" ::: "memory")

// One scan step. Consumes ring regs (M0,M1,XS); reloads them (for step T+2)
// DIRECTLY (no copies) right after their last use.
#define SSTEP(T, M0, M1, XS) { \
  f32x2 m2[8]; \
  { unsigned mm0 = M0.x, mm1 = M0.y, mm2 = M0.z, mm3 = M0.w; \
    unsigned mm4 = M1.x, mm5 = M1.y, mm6 = M1.z, mm7 = M1.w; \
    m2[0] = bf2x2(mm0); m2[1] = bf2x2(mm1); m2[2] = bf2x2(mm2); m2[3] = bf2x2(mm3); \
    m2[4] = bf2x2(mm4); m2[5] = bf2x2(mm5); m2[6] = bf2x2(mm6); m2[7] = bf2x2(mm7); } \
  f32x2 accm = {0.f, 0.f}, accw = {0.f, 0.f}; \
  _Pragma("unroll") \
  for (int j = 0; j < 4; ++j){ \
    float4 sv = sp4[q * 4 + j]; \
    f32x2 lo = {sv.x, sv.y}, hi = {sv.z, sv.w}; \
    accm = fma2(lo, m2[2*j],   accm); \
    accm = fma2(hi, m2[2*j+1], accm); \
    accw = fma2(lo, w02[2*j],   accw); \
    accw = fma2(hi, w02[2*j+1], accw); \
  } \
  float d1 = qred(accm.x + accm.y); \
  float d2 = qred(accw.x + accw.y); \
  Pa += d1; \
  float rec = gelu_fast(Pa + d2 + br_r);      /* d2 has c0 folded in */ \
  if (q == 0) recurs[idx] = rec; \
  /* prefetch M for step T+2 into the just-consumed ring regs */ \
  { int _ns = (T) < 2048 ? (T) : 2047; \
    const uint4* _p = mt4 + (size_t)_ns * 512 + moff; \
    M0 = _p[0]; M1 = _p[1]; } \
  BARRIER_LG(); \
  f32x2 accb = {0.f, 0.f}; \
  _Pragma("unroll") \
  for (int j = 0; j < 4; ++j){ \
    float4 rv = rc4[q * 4 + j]; \
    f32x2 lo = {rv.x, rv.y}, hi = {rv.z, rv.w}; \
    accb = fma2(lo, ws2[2*j],   accb); \
    accb = fma2(hi, ws2[2*j+1], accb); \
  } \
  float a2s = qred(accb.x + accb.y); \
  float stt = gelu_fast(a2s + XS + bs_s); \
  if (q == 0){ sprev[idx] = stt; sb[(size_t)((T) - 1) * 64 + idx] = stt; } \
  /* prefetch xstat for step T+2 directly into XS (last use was above) */ \
  { int _nx = (T) + 1 < 2048 ? (T) + 1 : 2047; \
    XS = xsp[(size_t)_nx * 64 + idx]; } \
  BARRIER_LG(); \
}

__global__ __launch_bounds__(512) void k_scan(
    const float* __restrict__ Wr, const float* __restrict__ br,
    const float* __restrict__ Ws, const float* __restrict__ bs,
    const float* __restrict__ phases, const float* __restrict__ xstat,
    const u16* __restrict__ MT, float* __restrict__ statsbuf){
  int tid = threadIdx.x;
  int g = tid >> 8;                      // sub-group 0/1 -> batch
  int b = blockIdx.x * 2 + g;
  int stid = tid & 255;
  int w = stid >> 6, l = stid & 63;
  int idx = w * 16 + (l >> 2);
  int q = l & 3;
  __shared__ __align__(16) float4 sprev4[2][16];
  __shared__ __align__(16) float4 recur4[2][16];
  const float4* sp4 = sprev4[g];
  const float4* rc4 = recur4[g];
  float* sprev  = (float*)sprev4[g];
  float* recurs = (float*)recur4[g];
  float c0 = INV_L * cosf(TWO_PI * phases[0]);
  // resident weight columns as float2 pairs (c0 folded into Wr0 column)
  f32x2 w02[8], ws2[8];
#pragma unroll
  for (int i = 0; i < 8; ++i){
    w02[i].x = c0 * Wr[(q * 16 + 2 * i) * 64 + idx];
    w02[i].y = c0 * Wr[(q * 16 + 2 * i + 1) * 64 + idx];
    ws2[i].x = Ws[(128 + q * 16 + 2 * i) * 64 + idx];
    ws2[i].y = Ws[(128 + q * 16 + 2 * i + 1) * 64 + idx];
  }
  float br_r = br[idx];
  float bs_s = bs[idx];
  float Pa = 0.0f;
  if (stid < 64) sprev[stid] = 0.0f;
  const uint4* mt4 = (const uint4*)MT;       // 512 uint4 per slot
  int moff = idx * 8 + q * 2;
  const float* xsp = xstat + (size_t)b * 2048 * 64;
  float* sb = statsbuf + (size_t)b * 2048 * 64;
  // 2-deep ring: step t uses M slot max(t-2,0) and xstat index t-1.
  // Prologue: A serves t=1 (slot 0, value irrelevant: sprev=0), B serves t=2 (slot 0).
  uint4 mA0, mA1, mB0, mB1;
  float xsA, xsB;
  { const uint4* _p = mt4 + moff; mA0 = _p[0]; mA1 = _p[1]; }
  { const uint4* _p = mt4 + moff; mB0 = _p[0]; mB1 = _p[1]; }
  xsA = xsp[idx];                  // t=1 -> index 0
  xsB = xsp[64 + idx];             // t=2 -> index 1
  __syncthreads();
  for (int t = 1; t <= 2048; t += 2){
    SSTEP(t,     mA0, mA1, xsA);
    SSTEP(t + 1, mB0, mB1, xsB);
  }
}

// --------------------------- K4: state materialization (bf16) ---------------
// state[b,t,f*64+s]: f>=1 cumsum of c_f(t)*stats; f=0 current term only.
__global__ __launch_bounds__(256) void k_state(const float* __restrict__ statsbuf,
    const float* __restrict__ ctab, u16* __restrict__ stateA){
  int g = blockIdx.x * 256 + threadIdx.x;       // [0, 32768)
  int s = g & 63, f = (g >> 6) & 15, b = g >> 10;
  const float* sp = statsbuf + (size_t)b * 2048 * 64 + s;
  u16* op = stateA + (size_t)b * 2048 * 1024 + f * 64 + s;
  float acc = 0.0f;
  const bool f0 = (f == 0);
  for (int t0 = 0; t0 < 2048; t0 += 8){
    float sv[8], cv[8];
#pragma unroll
    for (int i = 0; i < 8; ++i) sv[i] = sp[(size_t)(t0 + i) * 64];
#pragma unroll
    for (int i = 0; i < 8; ++i) cv[i] = ctab[(t0 + i + 1) * 16 + f];
#pragma unroll
    for (int i = 0; i < 8; ++i){
      acc = f0 ? (cv[i] * sv[i]) : fmaf(cv[i], sv[i], acc);
      op[(size_t)(t0 + i) * 1024] = f2bf(acc);
    }
  }
}

// --------------------------- K5: out = gelu(state @ Wo + bo) ----------------
// bf16 MFMA GEMM, 128x128 tile, 4 waves, 16x16x32, BT layout in LDS.
__global__ __launch_bounds__(256) void k_gemm(const u16* __restrict__ A,
    const u16* __restrict__ Bt, const float* __restrict__ bo, float* __restrict__ out){
  int nt = blockIdx.x & 7, mt = blockIdx.x >> 3;
  int m0 = mt * 128, n0 = nt * 128;
  __shared__ __align__(16) u16 As[128 * 32];
  __shared__ __align__(16) u16 Bs[128 * 32];
  int tid = threadIdx.x;
  int w = tid >> 6, l = tid & 63;
  int mh = (w & 1) * 64, nh = (w >> 1) * 64;
  int lr = l & 15, lq = l >> 4;
  f32x4 acc[4][4] = {};
  for (int k0 = 0; k0 < 1024; k0 += 32){
    int c = tid;
#pragma unroll
    for (int rr = 0; rr < 2; ++rr, c += 256){
      int row = c >> 2, qq = c & 3;
      *((uint4*)&As[row * 32 + qq * 8]) = *(const uint4*)(A  + (size_t)(m0 + row) * 1024 + k0 + qq * 8);
      *((uint4*)&Bs[row * 32 + qq * 8]) = *(const uint4*)(Bt + (size_t)(n0 + row) * 1024 + k0 + qq * 8);
    }
    __syncthreads();
    bf16x8 af[4], bfr[4];
#pragma unroll
    for (int i = 0; i < 4; ++i) af[i]  = *(const bf16x8*)&As[(mh + i * 16 + lr) * 32 + lq * 8];
#pragma unroll
    for (int i = 0; i < 4; ++i) bfr[i] = *(const bf16x8*)&Bs[(nh + i * 16 + lr) * 32 + lq * 8];
#pragma unroll
    for (int i = 0; i < 4; ++i)
#pragma unroll
      for (int j = 0; j < 4; ++j)
        acc[i][j] = __builtin_amdgcn_mfma_f32_16x16x32_bf16(af[i], bfr[j], acc[i][j], 0, 0, 0);
    __syncthreads();
  }
#pragma unroll
  for (int i = 0; i < 4; ++i){
#pragma unroll
    for (int j = 0; j < 4; ++j){
      int n = n0 + nh + j * 16 + lr;
      float bias = bo[n];
#pragma unroll
      for (int rg = 0; rg < 4; ++rg){
        int m = m0 + mh + i * 16 + lq * 4 + rg;
        out[(size_t)m * 1024 + n] = gelu_erf(acc[i][j][rg] + bias);
      }
    }
  }
}

// --------------------------- launcher ---------------------------------------
extern "C" void kernel_launch(void* const* d_in, const int* in_sizes, int n_in,
                              void* d_out, int out_size, void* d_ws, size_t ws_size,
                              hipStream_t stream){
  const float* x  = (const float*)d_in[0];
  const float* Wr = (const float*)d_in[1];
  const float* br = (const float*)d_in[2];
  const float* Ws = (const float*)d_in[3];
  const float* bs = (const float*)d_in[4];
  const float* Wo = (const float*)d_in[5];
  const float* bo = (const float*)d_in[6];
  const float* ph = (const float*)d_in[7];
  float* out = (float*)d_out;

  char* wp = (char*)d_ws;
  float* xstat    = (float*)(wp);                     // 16 MB: 65536 x 64 f32
  float* statsbuf = (float*)(wp + 16777216);          // 16 MB: 32 x 2048 x 64 f32
  u16*   MT       = (u16*)  (wp + 33554432);          // 16 MB: 2048 x 64 x 64 bf16
  float* ctab     = (float*)(wp + 50331648);          // 128 KB: 2049 x 16 f32
  u16*   WoT      = (u16*)  (wp + 50593792);          // 2 MB: 1024 x 1024 bf16
  u16*   stateA   = (u16*)  (wp + 52690944);          // 128 MB: 65536 x 1024 bf16

  hipLaunchKernelGGL(k_mprep, dim3(2048), dim3(256), 0, stream, Wr, ph, MT, ctab);
  hipLaunchKernelGGL(k_xstat, dim3(1024), dim3(256), 0, stream, x, Ws, xstat);
  hipLaunchKernelGGL(k_wot,   dim3(256),  dim3(256), 0, stream, Wo, WoT);
  hipLaunchKernelGGL(k_scan,  dim3(16),   dim3(512), 0, stream, Wr, br, Ws, bs, ph, xstat, MT, statsbuf);
  hipLaunchKernelGGL(k_state, dim3(128),  dim3(256), 0, stream, statsbuf, ctab, stateA);
  hipLaunchKernelGGL(k_gemm,  dim3(4096), dim3(256), 0, stream, stateA, WoT, bo, out);
}